// Round 11
// baseline (152.545 us; speedup 1.0000x reference)
//
#include <hip/hip_runtime.h>

#define H 1024
#define BSZ 64
#define TT 512
#define BT (BSZ * TT)   // 32768 rows
#define NSPLIT 4        // N=1024 / BN=256
#define NTILES 16       // K tiles = H / 64

using bf16x8 = __attribute__((ext_vector_type(8))) __bf16;
using f32x4  = __attribute__((ext_vector_type(4))) float;

__device__ __forceinline__ unsigned short f2bf(float f) {
  unsigned u = __float_as_uint(f);
  u += 0x7FFF + ((u >> 16) & 1);   // RTN-even
  return (unsigned short)(u >> 16);
}
__device__ __forceinline__ float bf2f(unsigned short h) {
  return __uint_as_float(((unsigned)h) << 16);
}

#define GLDS(gp, lp) \
  __builtin_amdgcn_global_load_lds( \
      (const __attribute__((address_space(1))) void*)(gp), \
      (__attribute__((address_space(3))) void*)(lp), 16, 0, 0)

// ---------------- Kernel 1: LayerNorm + bf16 cast ----------------
__global__ __launch_bounds__(256) void ln_kernel(
    const float* __restrict__ in, const float* __restrict__ gamma,
    const float* __restrict__ beta, unsigned short* __restrict__ xb) {
  const int row = blockIdx.x;
  const int tid = threadIdx.x;
  const float4 xv = reinterpret_cast<const float4*>(in + (size_t)row * H)[tid];
  float s  = xv.x + xv.y + xv.z + xv.w;
  float ss = xv.x * xv.x + xv.y * xv.y + xv.z * xv.z + xv.w * xv.w;
#pragma unroll
  for (int off = 32; off >= 1; off >>= 1) {
    s  += __shfl_xor(s, off);
    ss += __shfl_xor(ss, off);
  }
  __shared__ float red[2][4];
  const int w = tid >> 6;
  if ((tid & 63) == 0) { red[0][w] = s; red[1][w] = ss; }
  __syncthreads();
  const float tot  = red[0][0] + red[0][1] + red[0][2] + red[0][3];
  const float tot2 = red[1][0] + red[1][1] + red[1][2] + red[1][3];
  const float mu   = tot * (1.0f / H);
  const float var  = tot2 * (1.0f / H) - mu * mu;
  const float rstd = rsqrtf(var + 1e-5f);
  const float4 g  = reinterpret_cast<const float4*>(gamma)[tid];
  const float4 bt = reinterpret_cast<const float4*>(beta)[tid];
  ushort4 o;
  o.x = f2bf((xv.x - mu) * rstd * g.x + bt.x);
  o.y = f2bf((xv.y - mu) * rstd * g.y + bt.y);
  o.z = f2bf((xv.z - mu) * rstd * g.z + bt.z);
  o.w = f2bf((xv.w - mu) * rstd * g.w + bt.w);
  reinterpret_cast<ushort4*>(xb + (size_t)row * H)[tid] = o;
}

// ---------------- Kernel 2: W -> bf16 ----------------
__global__ __launch_bounds__(256) void wcvt_kernel(
    const float* __restrict__ Win, unsigned short* __restrict__ wb) {
  const size_t i = (size_t)blockIdx.x * 1024 + (size_t)threadIdx.x * 4;
  const float4 xv = *reinterpret_cast<const float4*>(Win + i);
  ushort4 o;
  o.x = f2bf(xv.x); o.y = f2bf(xv.y); o.z = f2bf(xv.z); o.w = f2bf(xv.w);
  *reinterpret_cast<ushort4*>(wb + i) = o;
}

// ---------------- Kernel 3: fused scores GEMM (256x256, asm-pinned pipe)
// spart[nt][m] = sum_{d in [nt*256,nt*256+256)} tanh(Wout[m,d]+bW[d])*v[d]
//
// Phase (one per kh, 2 per K-tile):
//   s_waitcnt vmcnt(4)   ; region being read this phase fully staged
//   s_barrier            ; all waves' writes visible
//   12x volatile-asm ds_read_b128 -> frag set for NEXT phase (unmovable)
//   4x GLDS stage of region used 3 phases later
//   s_waitcnt lgkmcnt(12); sched_barrier(0)  ; THIS phase's frags retired
//                                            ; (DS retires in order),
//                                            ; 12 new reads stay in flight
//   setprio(1); 32 MFMA on current frag set; setprio(0); sched_barrier(0)
// Frag sets ping-pong (fa0/fb0 = kh0, fa1/fb1 = kh1) -> DS pipe and MFMA
// pipe overlap across phases; compiler cannot serialize (asm-pinned).
// Region(buf,kh) byte base = (buf*2+kh)*16384 in As/Bs. Stage schedule:
// kh0(t) stages (t+1,kh1); kh1(t) stages (t+2,kh0). vmcnt(4) retires the
// 2-phases-ago batch = exactly the region read this phase. Tail peeled.
__global__ __launch_bounds__(512, 2) void score_gemm(
    const unsigned short* __restrict__ xb, const unsigned short* __restrict__ wb,
    const float* __restrict__ bW, const float* __restrict__ v,
    float* __restrict__ spart) {
  __shared__ unsigned short As[32768];
  __shared__ unsigned short Bs[32768];
  __shared__ float s_red[4][256];

  const int tid  = threadIdx.x;
  const int w    = tid >> 6, lane = tid & 63;
  const int wm   = w >> 2, wn = w & 3;      // 2 M-waves x 4 N-waves

  // bijective XCD swizzle (512 blocks % 8 == 0)
  const int bid0 = blockIdx.x;
  const int bid  = (bid0 & 7) * 64 + (bid0 >> 3);
  const int mt = bid & 127, nt = bid >> 7;
  const int mbase = mt * 256, nbase = nt * 256;

  // --- staging geometry (verified R2-R10): one unit = 256 rows x 32 k ---
  const int srow = lane >> 2;
  const int swz8 = ((lane & 3) ^ ((lane >> 3) & 3)) * 8;   // pre-swizzled src col
  const int ch0 = w, ch1 = 8 + w;
  const unsigned short* gA0r = xb + (size_t)(mbase + ch0 * 16 + srow) * H + swz8;
  const unsigned short* gA1r = xb + (size_t)(mbase + ch1 * 16 + srow) * H + swz8;
  const unsigned short* gB0r = wb + (size_t)(nbase + ch0 * 16 + srow) * H + swz8;
  const unsigned short* gB1r = wb + (size_t)(nbase + ch1 * 16 + srow) * H + swz8;

#define STAGE_R(T, KH, BUF) { \
    const int co = (T) * 64 + (KH) * 32; \
    const int ro = ((BUF) * 2 + (KH)) * 8192; \
    GLDS(gA0r + co, &As[ro + ch0 * 512]); \
    GLDS(gA1r + co, &As[ro + ch1 * 512]); \
    GLDS(gB0r + co, &Bs[ro + ch0 * 512]); \
    GLDS(gB1r + co, &Bs[ro + ch1 * 512]); }

  // --- fragment-read geometry (swizzle-matched) ---
  const int acoff = (((lane >> 4) ^ (((lane & 15) >> 1) & 3)) * 8);
  const int arow0 = wm * 128 + (lane & 15);
  const int brow0 = wn * 64  + (lane & 15);
  const unsigned abase = (unsigned)(uintptr_t)&As[arow0 * 32 + acoff];
  const unsigned bbase = (unsigned)(uintptr_t)&Bs[brow0 * 32 + acoff];

#define DSR(dst, base, imm) \
  asm volatile("ds_read_b128 %0, %1 offset:%2" : "=&v"(dst) : "v"(base), "i"(imm))

#define READS(FA, FB, RIMM) \
  DSR(FA[0], abase, (RIMM) + 0 * 1024); \
  DSR(FA[1], abase, (RIMM) + 1 * 1024); \
  DSR(FA[2], abase, (RIMM) + 2 * 1024); \
  DSR(FA[3], abase, (RIMM) + 3 * 1024); \
  DSR(FA[4], abase, (RIMM) + 4 * 1024); \
  DSR(FA[5], abase, (RIMM) + 5 * 1024); \
  DSR(FA[6], abase, (RIMM) + 6 * 1024); \
  DSR(FA[7], abase, (RIMM) + 7 * 1024); \
  DSR(FB[0], bbase, (RIMM) + 0 * 1024); \
  DSR(FB[1], bbase, (RIMM) + 1 * 1024); \
  DSR(FB[2], bbase, (RIMM) + 2 * 1024); \
  DSR(FB[3], bbase, (RIMM) + 3 * 1024);

#define MM32(FA, FB) \
  __builtin_amdgcn_s_setprio(1); \
  _Pragma("unroll") \
  for (int mi = 0; mi < 8; mi++) \
    _Pragma("unroll") \
    for (int ni = 0; ni < 4; ni++) \
      acc[mi][ni] = __builtin_amdgcn_mfma_f32_16x16x32_bf16(FA[mi], FB[ni], acc[mi][ni], 0, 0, 0); \
  __builtin_amdgcn_s_setprio(0); \
  __builtin_amdgcn_sched_barrier(0);

#define NOSTAGE ((void)0)

#define PH(FN, GN, RIMM, STG, FC, GC, VMSTR) \
  asm volatile("s_waitcnt " VMSTR ::: "memory"); \
  __builtin_amdgcn_s_barrier(); \
  READS(FN, GN, RIMM) \
  STG; \
  asm volatile("s_waitcnt lgkmcnt(12)" ::: "memory"); \
  __builtin_amdgcn_sched_barrier(0); \
  MM32(FC, GC)

  f32x4 acc[8][4];
#pragma unroll
  for (int mi = 0; mi < 8; mi++)
#pragma unroll
    for (int ni = 0; ni < 4; ni++) acc[mi][ni] = (f32x4){0.f, 0.f, 0.f, 0.f};

  bf16x8 fa0[8], fb0[4], fa1[8], fb1[4];

  // prologue: regions (0,0),(0,1),(1,0); retire (0,0); read kh0 frags
  STAGE_R(0, 0, 0)
  STAGE_R(0, 1, 0)
  STAGE_R(1, 0, 1)
  asm volatile("s_waitcnt vmcnt(8)" ::: "memory");
  __builtin_amdgcn_s_barrier();
  READS(fa0, fb0, 0)

  for (int t = 0; t < 14; t += 2) {
    // even t kh0: read (0,1); stage (t+1,kh1)->buf1; MFMA kh0
    PH(fa1, fb1, 16384, STAGE_R(t + 1, 1, 1), fa0, fb0, "vmcnt(4)")
    // even t kh1: read (1,0); stage (t+2,kh0)->buf0; MFMA kh1
    PH(fa0, fb0, 32768, STAGE_R(t + 2, 0, 0), fa1, fb1, "vmcnt(4)")
    // odd t+1 kh0: read (1,1); stage (t+2,kh1)->buf0; MFMA kh0
    PH(fa1, fb1, 49152, STAGE_R(t + 2, 1, 0), fa0, fb0, "vmcnt(4)")
    // odd t+1 kh1: read (0,0); stage (t+3,kh0)->buf1; MFMA kh1
    PH(fa0, fb0, 0,     STAGE_R(t + 3, 0, 1), fa1, fb1, "vmcnt(4)")
  }
  // t = 14 (even)
  PH(fa1, fb1, 16384, STAGE_R(15, 1, 1), fa0, fb0, "vmcnt(4)")
  PH(fa0, fb0, 32768, NOSTAGE,           fa1, fb1, "vmcnt(4)")
  // t = 15 (odd) — tail
  PH(fa1, fb1, 49152, NOSTAGE,           fa0, fb0, "vmcnt(0)")
  asm volatile("s_waitcnt lgkmcnt(0)" ::: "memory");
  __builtin_amdgcn_sched_barrier(0);
  MM32(fa1, fb1)

  // ---- epilogue: tanh(.+bW)*v, reduce over N within block ----
  float sp[8][4];
#pragma unroll
  for (int mi = 0; mi < 8; mi++)
#pragma unroll
    for (int r = 0; r < 4; r++) sp[mi][r] = 0.f;

#pragma unroll
  for (int ni = 0; ni < 4; ni++) {
    const int col = nbase + wn * 64 + ni * 16 + (lane & 15);
    const float bwv = bW[col];
    const float vv  = v[col];
#pragma unroll
    for (int mi = 0; mi < 8; mi++)
#pragma unroll
      for (int r = 0; r < 4; r++) {
        float xv = acc[mi][ni][r] + bwv;
        xv = fminf(fmaxf(xv, -15.f), 15.f);
        const float e = __expf(2.f * xv);
        sp[mi][r] += vv * (e - 1.f) / (e + 1.f);   // tanh
      }
  }
#pragma unroll
  for (int mi = 0; mi < 8; mi++)
#pragma unroll
    for (int r = 0; r < 4; r++) {
      float sv = sp[mi][r];
      sv += __shfl_xor(sv, 1);
      sv += __shfl_xor(sv, 2);
      sv += __shfl_xor(sv, 4);
      sv += __shfl_xor(sv, 8);
      sp[mi][r] = sv;
    }
  if ((lane & 15) == 0) {
#pragma unroll
    for (int mi = 0; mi < 8; mi++)
#pragma unroll
      for (int r = 0; r < 4; r++)
        s_red[wn][wm * 128 + mi * 16 + (lane >> 4) * 4 + r] = sp[mi][r];
  }
  __syncthreads();
  if (tid < 256)
    spart[(size_t)nt * BT + mbase + tid] =
        s_red[0][tid] + s_red[1][tid] + s_red[2][tid] + s_red[3][tid];
}

// ---------------- Kernel 4: softmax over T per batch ----------------
__global__ __launch_bounds__(512) void softmax_kernel(
    const float* __restrict__ spart, const float* __restrict__ bv,
    float* __restrict__ wout) {
  const int b = blockIdx.x, t = threadIdx.x;
  float s = bv[0];
#pragma unroll
  for (int p = 0; p < NSPLIT; p++) s += spart[(size_t)p * BT + b * TT + t];
  if (s != s) s = 0.f;                       // nan_to_num
  s = fminf(fmaxf(s, -10.f), 10.f);          // clip
  float m = s;
#pragma unroll
  for (int off = 32; off >= 1; off >>= 1) m = fmaxf(m, __shfl_xor(m, off));
  __shared__ float redm[8], reds[8];
  const int w = t >> 6;
  if ((t & 63) == 0) redm[w] = m;
  __syncthreads();
  m = redm[0];
#pragma unroll
  for (int i = 1; i < 8; i++) m = fmaxf(m, redm[i]);
  const float e = expf(s - m);
  float su = e;
#pragma unroll
  for (int off = 32; off >= 1; off >>= 1) su += __shfl_xor(su, off);
  if ((t & 63) == 0) reds[w] = su;
  __syncthreads();
  su = 0.f;
#pragma unroll
  for (int i = 0; i < 8; i++) su += reds[i];
  wout[b * TT + t] = e / su;
}

// ---------------- Kernel 5: context partials over t-chunks ----------------
__global__ __launch_bounds__(256) void ctx_part_kernel(
    const unsigned short* __restrict__ xb, const float* __restrict__ wts,
    float* __restrict__ ctxp) {
  const int b = blockIdx.x, c = blockIdx.y, tid = threadIdx.x;
  const int h = tid * 4;
  float a0 = 0.f, a1 = 0.f, a2 = 0.f, a3 = 0.f;
  const unsigned short* xrow = xb + ((size_t)(b * TT + c * 64)) * H + h;
  const float* wrow = wts + b * TT + c * 64;
  for (int t = 0; t < 64; t++) {
    const float wgt = wrow[t];
    const ushort4 xv = *reinterpret_cast<const ushort4*>(xrow + (size_t)t * H);
    a0 += wgt * bf2f(xv.x);
    a1 += wgt * bf2f(xv.y);
    a2 += wgt * bf2f(xv.z);
    a3 += wgt * bf2f(xv.w);
  }
  float4 o = {a0, a1, a2, a3};
  *reinterpret_cast<float4*>(ctxp + ((size_t)c * BSZ + b) * H + h) = o;
}

// ---------------- Kernel 6: context reduce ----------------
__global__ __launch_bounds__(256) void ctx_reduce_kernel(
    const float* __restrict__ ctxp, float* __restrict__ out) {
  const int idx = blockIdx.x * 256 + threadIdx.x;  // 0..65535 = b*H+h
  float s = 0.f;
#pragma unroll
  for (int c = 0; c < 8; c++) s += ctxp[(size_t)c * (BSZ * H) + idx];
  out[idx] = s;
}

extern "C" void kernel_launch(void* const* d_in, const int* in_sizes, int n_in,
                              void* d_out, int out_size, void* d_ws, size_t ws_size,
                              hipStream_t stream) {
  const float* lstm  = (const float*)d_in[0];
  const float* W     = (const float*)d_in[1];
  const float* bW    = (const float*)d_in[2];
  const float* v     = (const float*)d_in[3];
  const float* bv    = (const float*)d_in[4];
  const float* gamma = (const float*)d_in[5];
  const float* beta  = (const float*)d_in[6];
  float* out = (float*)d_out;

  char* ws = (char*)d_ws;
  unsigned short* xb = (unsigned short*)ws;                                   // 64 MiB
  unsigned short* wb = (unsigned short*)(ws + (size_t)BT * H * 2);            // 2 MiB
  float* spart = (float*)(ws + (size_t)BT * H * 2 + (size_t)H * H * 2);       // 512 KiB
  float* ctxp  = (float*)((char*)spart + (size_t)NSPLIT * BT * 4);            // 2 MiB

  float* weights_out = out + BSZ * H;   // context first (65536), then weights (32768)

  ln_kernel<<<BT, 256, 0, stream>>>(lstm, gamma, beta, xb);
  wcvt_kernel<<<(H * H) / 1024, 256, 0, stream>>>(W, wb);
  score_gemm<<<512, 512, 0, stream>>>(xb, wb, bW, v, spart);
  softmax_kernel<<<BSZ, TT, 0, stream>>>(spart, bv, weights_out);
  ctx_part_kernel<<<dim3(BSZ, 8), 256, 0, stream>>>(xb, weights_out, ctxp);
  ctx_reduce_kernel<<<(BSZ * H) / 256, 256, 0, stream>>>(ctxp, out);
}